// Round 5
// baseline (1448.783 us; speedup 1.0000x reference)
//
#include <hip/hip_runtime.h>
#include <hip/hip_bf16.h>
#include <stdint.h>

// GraphSAGE layer, N=16384, F_IN=F_OUT=256.
// out = (adj@ (x@W1))/deg + x@W2 + bias
//   K0: WT[n][k] (bf16)  = transpose of [W1|W2]
//   K1: yTt[j/32][n][32] (bf16, K-TILED) = (x@W1)^T ; z[m][n] = x@W2 + bias
//   K2 v13: split-K 3 (5472/5472/5440), 768 blocks = 3 blocks/CU (the TLP
//          lever: v10 proved 1/CU = +238us, so stalls are hidden by
//          co-resident blocks). LDS 40 KB: A dbuf linear [64][32] + B dbuf
//          linear [256][32], both XOR-swizzled (slot ^ ((row>>1)&3), 16B
//          granule; applied to GLOBAL source addr + frag ds_read — LDS dest
//          stays linear for global_load_lds). B staged via global_load_lds
//          width 16 (no VGPR round-trip). Counted s_waitcnt
//          vmcnt(1) lgkmcnt(0) before each raw s_barrier (A load in flight
//          across barriers; never a full drain in-loop).
//   K3: out = (p0+p1+p2)/(d0+d1+d2) + z

typedef short bf16x8 __attribute__((ext_vector_type(8)));
typedef float f32x4  __attribute__((ext_vector_type(4)));
typedef int   i32x4  __attribute__((ext_vector_type(4)));

__device__ __forceinline__ uint32_t pack_bf16_rne(float lo, float hi) {
    uint32_t ul = __float_as_uint(lo);
    uint32_t uh = __float_as_uint(hi);
    ul = (ul + 0x7fffu + ((ul >> 16) & 1u)) >> 16;
    uh = (uh + 0x7fffu + ((uh >> 16) & 1u)) >> 16;
    return ul | (uh << 16);
}

__device__ __forceinline__ void gld_lds16(const uint16_t* g, uint16_t* l) {
    __builtin_amdgcn_global_load_lds(
        (const __attribute__((address_space(1))) void*)g,
        (__attribute__((address_space(3))) void*)l, 16, 0, 0);
}

// ---------------- K0: transpose weight [512,256] f32 -> WT [512(n)][256(k)] bf16
__global__ __launch_bounds__(256) void k_transpose_w(const float* __restrict__ w,
                                                     uint16_t* __restrict__ wt) {
    int idx = blockIdx.x * 256 + threadIdx.x;   // 0..131071
    int n = idx >> 8;
    int k = idx & 255;
    int row = (n < 256) ? k : (256 + k);
    int col = (n < 256) ? n : (n - 256);
    uint32_t u = __float_as_uint(w[row * 256 + col]);
    u = (u + 0x7fffu + ((u >> 16) & 1u)) >> 16;
    wt[idx] = (uint16_t)u;
}

// ---------------- K1: small GEMM  [16384,256] @ [256,512]
// -> yTt (K-tiled transpose, cols 0..255) / z (cols 256..511)
__global__ __launch_bounds__(256) void k_small_gemm(const float* __restrict__ x,
                                                    const uint16_t* __restrict__ wt,
                                                    const float* __restrict__ bias,
                                                    uint16_t* __restrict__ yTt,
                                                    float* __restrict__ z) {
    __shared__ uint16_t As[128 * 32];  // [m][k] bf16
    __shared__ uint16_t Bs[128 * 32];  // [n][k] bf16

    const int t  = threadIdx.x;
    const int ct = blockIdx.x;        // 0..3
    const int rt = blockIdx.y;        // 0..127
    const int m0 = rt * 128;
    const int n0 = ct * 128;

    const int lane = t & 63, w = t >> 6;
    const int wr = w >> 1, wc = w & 1;
    const int l15 = lane & 15, quad = lane >> 4;

    f32x4 acc[4][4] = {};

    float4 a_reg[4];
    uint4  b_reg[2];

#pragma unroll
    for (int i = 0; i < 4; ++i) {
        int f4 = t + 256 * i, row = f4 >> 3, c4 = f4 & 7;
        a_reg[i] = *(const float4*)(x + (m0 + row) * 256 + c4 * 4);
    }
#pragma unroll
    for (int i = 0; i < 2; ++i) {
        int u4 = t + 256 * i, n_l = u4 >> 2, part = u4 & 3;
        b_reg[i] = *(const uint4*)(wt + (n0 + n_l) * 256 + part * 8);
    }

    for (int kk = 0; kk < 8; ++kk) {
        __syncthreads();
#pragma unroll
        for (int i = 0; i < 4; ++i) {
            int f4 = t + 256 * i, row = f4 >> 3, c4 = f4 & 7;
            uint2 p;
            p.x = pack_bf16_rne(a_reg[i].x, a_reg[i].y);
            p.y = pack_bf16_rne(a_reg[i].z, a_reg[i].w);
            *(uint2*)(As + row * 32 + c4 * 4) = p;
        }
#pragma unroll
        for (int i = 0; i < 2; ++i) {
            int u4 = t + 256 * i, n_l = u4 >> 2, part = u4 & 3;
            *(uint4*)(Bs + n_l * 32 + part * 8) = b_reg[i];
        }
        if (kk < 7) {
            int k0 = (kk + 1) * 32;
#pragma unroll
            for (int i = 0; i < 4; ++i) {
                int f4 = t + 256 * i, row = f4 >> 3, c4 = f4 & 7;
                a_reg[i] = *(const float4*)(x + (m0 + row) * 256 + k0 + c4 * 4);
            }
#pragma unroll
            for (int i = 0; i < 2; ++i) {
                int u4 = t + 256 * i, n_l = u4 >> 2, part = u4 & 3;
                b_reg[i] = *(const uint4*)(wt + (n0 + n_l) * 256 + k0 + part * 8);
            }
        }
        __syncthreads();

        bf16x8 a_frag[4], b_frag[4];
#pragma unroll
        for (int fr = 0; fr < 4; ++fr)
            a_frag[fr] = *(const bf16x8*)(As + (wr * 64 + fr * 16 + l15) * 32 + quad * 8);
#pragma unroll
        for (int fc = 0; fc < 4; ++fc)
            b_frag[fc] = *(const bf16x8*)(Bs + (wc * 64 + fc * 16 + l15) * 32 + quad * 8);
#pragma unroll
        for (int fr = 0; fr < 4; ++fr)
#pragma unroll
            for (int fc = 0; fc < 4; ++fc)
                acc[fr][fc] = __builtin_amdgcn_mfma_f32_16x16x32_bf16(
                    a_frag[fr], b_frag[fc], acc[fr][fc], 0, 0, 0);
    }

    if (ct < 2) {
        // y^T K-tiled: yTt[(m>>5)][n][32] + (m&31); lane's 4 regs = 4
        // consecutive m inside one 32-tile (m_base%32 <= 28) -> one uint2
#pragma unroll
        for (int fr = 0; fr < 4; ++fr) {
            int m_base = m0 + wr * 64 + fr * 16 + quad * 4;
#pragma unroll
            for (int fc = 0; fc < 4; ++fc) {
                int n_g = n0 + wc * 64 + fc * 16 + l15;   // 0..255
                uint2 pp;
                pp.x = pack_bf16_rne(acc[fr][fc][0], acc[fr][fc][1]);
                pp.y = pack_bf16_rne(acc[fr][fc][2], acc[fr][fc][3]);
                *(uint2*)(yTt + (size_t)(m_base >> 5) * 8192 + n_g * 32 + (m_base & 31)) = pp;
            }
        }
    } else {
#pragma unroll
        for (int fr = 0; fr < 4; ++fr) {
            int m_base = m0 + wr * 64 + fr * 16 + quad * 4;
#pragma unroll
            for (int fc = 0; fc < 4; ++fc) {
                int n_g = (n0 - 256) + wc * 64 + fc * 16 + l15;  // 0..255
                float bv = bias[n_g];
#pragma unroll
                for (int r = 0; r < 4; ++r)
                    z[(size_t)(m_base + r) * 256 + n_g] = acc[fr][fc][r] + bv;
            }
        }
    }
}

// ---------------- K2 v13
// LDS: linear, XOR-swizzled on source+read (16B slot ^ ((row>>1)&3)).
// As[buf]: [64][32] hw = 4 KB each; Bs[buf]: [256][32] hw = 16 KB each.
// Step KK: DMA B(KK+1)->Bs[WR], load A(KK+2)->aN, stage A(KK+1)(q1)->As[WR],
// compute from As[RD]/Bs[RD], then s_waitcnt vmcnt(1) lgkmcnt(0); s_barrier.
#define STEP(RD, WR, KK)                                                        \
  do {                                                                          \
    if ((KK) < ns - 1) {  /* B(KK+1) DMA */                                     \
      gld_lds16(gB0, &Bs[WR][ldsB0]);                                           \
      gld_lds16(gB1, &Bs[WR][ldsB1]);                                           \
      gB0 += 8192; gB1 += 8192;                                                 \
    }                                                                           \
    if ((KK) < ns - 2) {  /* A(KK+2) regs, non-temporal */                      \
      aN = __builtin_nontemporal_load(pa4); pa4 += 8;                           \
    }                                                                           \
    if ((KK) < ns - 1) {  /* stage A(KK+1) */                                   \
      degp += q1.x + q1.y + q1.z + q1.w;                                        \
      uint2 pv;                                                                 \
      pv.x = (uint32_t)(q1.x | (q1.y << 16)) * 0x3F80u;                         \
      pv.y = (uint32_t)(q1.z | (q1.w << 16)) * 0x3F80u;                         \
      *(uint2*)&As[WR][a_wr] = pv;                                              \
    }                                                                           \
    {                                                                           \
      bf16x8 af[2];                                                             \
      _Pragma("unroll") for (int fr = 0; fr < 2; ++fr)                          \
        af[fr] = *(const bf16x8*)&As[RD][af_base + fr * 512];                   \
      _Pragma("unroll") for (int fh = 0; fh < 2; ++fh) {                        \
        bf16x8 bfr[2];                                                          \
        _Pragma("unroll") for (int fc = 0; fc < 2; ++fc)                        \
          bfr[fc] = *(const bf16x8*)&Bs[RD][bf_base + (fh * 2 + fc) * 512];     \
        __builtin_amdgcn_s_setprio(1);                                          \
        _Pragma("unroll") for (int fr = 0; fr < 2; ++fr)                        \
          _Pragma("unroll") for (int fc = 0; fc < 2; ++fc)                      \
            acc[fr][fh * 2 + fc] = __builtin_amdgcn_mfma_f32_16x16x32_bf16(     \
                af[fr], bfr[fc], acc[fr][fh * 2 + fc], 0, 0, 0);                \
        __builtin_amdgcn_s_setprio(0);                                          \
      }                                                                         \
    }                                                                           \
    q1 = aN;                                                                    \
    if ((KK) < ns - 2)                                                          \
      asm volatile("s_waitcnt vmcnt(1) lgkmcnt(0)\n\ts_barrier" ::: "memory");  \
    else                                                                        \
      asm volatile("s_waitcnt vmcnt(0) lgkmcnt(0)\n\ts_barrier" ::: "memory");  \
  } while (0)

__global__ __launch_bounds__(512, 6) void k_big_gemm(const int* __restrict__ adj,
                                                     const uint16_t* __restrict__ yTt,
                                                     float* __restrict__ part,
                                                     int* __restrict__ degw) {
    __shared__ __align__(16) uint16_t As[2][64 * 32];    // 8 KB
    __shared__ __align__(16) uint16_t Bs[2][256 * 32];   // 32 KB

    const int t = threadIdx.x;
    const int m0 = blockIdx.x * 64;
    const int ky = blockIdx.y;                     // 0..2; K chunks 5472/5472/5440
    const int ns = (ky == 2) ? 170 : 171;          // steps of BK=32
    const int lane = t & 63, w = t >> 6;
    const int wr = w >> 2, wc = w & 3;             // wave: 2 row frags, 4 col frags
    const int l15 = lane & 15, quad = lane >> 4;
    const int xorq = quad ^ ((l15 >> 1) & 3);      // 16B-slot XOR (same for A & B)

    f32x4 acc[2][4] = {};

    // A: 64 rows x 32 ints / step; thread -> row t>>3, int4 chunk t&7
    const int a_row = t >> 3, a_c4 = t & 7;
    const i32x4* pa4 = (const i32x4*)(adj + (size_t)(m0 + a_row) * 16384 + ky * 5472) + a_c4;
    // A stage write: 8B at swizzled slot
    const int a_wr = a_row * 32 + (((a_c4 >> 1) ^ ((a_row >> 1) & 3)) * 8) + (a_c4 & 1) * 4;

    // B DMA: chunk c = t + 512*j; LDS linear dest (wave base + lane*16B);
    // global source pre-XOR'd within the 64B row.
    const int c0 = t, c1 = t + 512;
    const size_t tile0 = (size_t)ky * 171;         // yTt tile index of chunk start
    const uint16_t* gB0 = yTt + tile0 * 8192
        + (c0 >> 2) * 32 + (((c0 & 3) ^ ((c0 >> 3) & 3)) * 8);
    const uint16_t* gB1 = yTt + tile0 * 8192
        + (c1 >> 2) * 32 + (((c1 & 3) ^ ((c1 >> 3) & 3)) * 8);
    const int ldsB0 = w * 512;                     // hw; + lane*8 by HW
    const int ldsB1 = w * 512 + 4096;

    // frag read bases (hw), swizzled; fr/fc offsets are +512 hw (1KB) immediates
    const int af_base = (wr * 32 + l15) * 32 + xorq * 8;
    const int bf_base = (wc * 64 + l15) * 32 + xorq * 8;

    i32x4 q1, aN;
    int degp;

    // ---- prologue: B(0) DMA -> Bs[0]; A(0)->a0, A(1)->q1; stage A(0)
    gld_lds16(gB0, &Bs[0][ldsB0]);
    gld_lds16(gB1, &Bs[0][ldsB1]);
    gB0 += 8192; gB1 += 8192;
    i32x4 a0 = __builtin_nontemporal_load(pa4); pa4 += 8;
    q1 = __builtin_nontemporal_load(pa4); pa4 += 8;
    aN = q1;
    degp = a0.x + a0.y + a0.z + a0.w;
    {
        uint2 pv;
        pv.x = (uint32_t)(a0.x | (a0.y << 16)) * 0x3F80u;
        pv.y = (uint32_t)(a0.z | (a0.w << 16)) * 0x3F80u;
        *(uint2*)&As[0][a_wr] = pv;
    }
    asm volatile("s_waitcnt vmcnt(1) lgkmcnt(0)\n\ts_barrier" ::: "memory");

    // ---- main loop
    int kk = 0;
    for (; kk + 1 < ns; kk += 2) {
        STEP(0, 1, kk);
        STEP(1, 0, kk + 1);
    }
    if (kk < ns) STEP(0, 1, kk);   // ns odd tail (ky 0/1: step 170)

    // partial deg: row a_row owned by 8 consecutive lanes
    degp += __shfl_down(degp, 4);
    degp += __shfl_down(degp, 2);
    degp += __shfl_down(degp, 1);
    if ((t & 7) == 0) degw[ky * 16384 + m0 + a_row] = degp;

    // partial C (C/D layout: col=lane&15, row=quad*4+reg) — non-temporal stores
    float* pc = part + (size_t)ky * 16384 * 256;
#pragma unroll
    for (int fr = 0; fr < 2; ++fr) {
#pragma unroll
        for (int r = 0; r < 4; ++r) {
            int m_l = wr * 32 + fr * 16 + quad * 4 + r;
            size_t mrow = (size_t)(m0 + m_l) * 256;
#pragma unroll
            for (int fc = 0; fc < 4; ++fc) {
                int n_g = wc * 64 + fc * 16 + l15;
                __builtin_nontemporal_store(acc[fr][fc][r], &pc[mrow + n_g]);
            }
        }
    }
}

// ---------------- K3: out = (p0+p1+p2)/(d0+d1+d2) + z
__global__ __launch_bounds__(256) void k_reduce(const float* __restrict__ part,
                                                const int* __restrict__ degw,
                                                const float* __restrict__ z,
                                                float* __restrict__ out) {
    int i4 = blockIdx.x * 256 + threadIdx.x;       // float4 index, 64 per row
    int m = i4 >> 6;
    float4 p0 = ((const float4*)part)[i4];
    float4 p1 = ((const float4*)part)[i4 + 16384 * 64];
    float4 p2 = ((const float4*)part)[i4 + 2 * 16384 * 64];
    float4 zz = ((const float4*)z)[i4];
    float inv = 1.0f / (float)(degw[m] + degw[16384 + m] + degw[32768 + m]);
    float4 o;
    o.x = (p0.x + p1.x + p2.x) * inv + zz.x;
    o.y = (p0.y + p1.y + p2.y) * inv + zz.y;
    o.z = (p0.z + p1.z + p2.z) * inv + zz.z;
    o.w = (p0.w + p1.w + p2.w) * inv + zz.w;
    ((float4*)out)[i4] = o;
}

extern "C" void kernel_launch(void* const* d_in, const int* in_sizes, int n_in,
                              void* d_out, int out_size, void* d_ws, size_t ws_size,
                              hipStream_t stream) {
    const float* x      = (const float*)d_in[0];
    const int*   adj    = (const int*)d_in[1];
    const float* weight = (const float*)d_in[2];
    const float* bias   = (const float*)d_in[3];
    float* out = (float*)d_out;

    // ws: WT 256KB | yTt 8MB | z 16MB | part 48MB | degw 192KB
    char* wsb = (char*)d_ws;
    uint16_t* wt   = (uint16_t*)(wsb);
    uint16_t* yTt  = (uint16_t*)(wsb + 262144);
    float*    z    = (float*)(wsb + 262144 + 8388608);
    float*    partb= (float*)(wsb + 262144 + 8388608 + 16777216);
    int*      degw = (int*)(wsb + 262144 + 8388608 + 16777216 + 50331648);

    k_transpose_w<<<512, 256, 0, stream>>>(weight, wt);
    k_small_gemm<<<dim3(4, 128), 256, 0, stream>>>(x, wt, bias, yTt, z);
    k_big_gemm<<<dim3(256, 3), 512, 0, stream>>>(adj, yTt, partb, degw);
    k_reduce<<<4096, 256, 0, stream>>>(partb, degw, z, out);
}